// Round 4
// baseline (297.239 us; speedup 1.0000x reference)
//
#include <hip/hip_runtime.h>

// Fused attention with masked-key compaction, 5 dispatches:
//  L1 prep:    cast x,W -> f16; zero zrow; per-batch mask scan (sel/counts/npad)
//  L2 qkv:     z=0..3 [K|V] = gather(x)@[Wk|Wv]^T+b (sel-indirect staging, M=npad)
//              z=4..5 Q = x@Wq^T+bq (all 8192 rows)
//  L3 scores:  z=0..3 S = (Q Kc^T)/32 (N=npad);  z=4..11 V-transpose slices
//  L4 softmax: compacted rows (pad cols -inf)
//  L5 pv:      O = P @ Vc^T (K=npad), fp32 out
// GEMM core: 128x128 tile, 4 waves, 4x4 16x16x32 f16 MFMA, BK=64, global_load_lds
// w=16, XOR-swizzled LDS (SQ_LDS_BANK_CONFLICT=0 verified R2).

typedef _Float16 f16;
typedef _Float16 f16x4 __attribute__((ext_vector_type(4)));
typedef _Float16 f16x8 __attribute__((ext_vector_type(8)));
typedef float f32x4 __attribute__((ext_vector_type(4)));

#define LB256 __launch_bounds__(256)

__device__ __forceinline__ void gld16(const void* gp, void* lp) {
  __builtin_amdgcn_global_load_lds(
      (__attribute__((address_space(1))) void*)(gp),
      (__attribute__((address_space(3))) void*)(lp),
      16, 0, 0);
}

// ---------------------------------------------------------------- GEMM body
// C[m,n] = scale * sum_k A[m,k]*B[n,k] + bias(n). A-rows optionally gathered
// through selrow (rows >= cnt read zrow). XOR-swizzled LDS staging.
template <typename OutT>
__device__ __forceinline__ void gemm_body(
    const f16* __restrict__ A, int lda,
    const int* __restrict__ selrow, int cnt, const f16* __restrict__ zrow,
    const f16* __restrict__ B, int ldb,
    OutT* __restrict__ C, int ldc,
    const float* __restrict__ bias1, const float* __restrict__ bias2, int nb1,
    float scale, int K, int m0, int n0) {
  __shared__ __align__(16) f16 As[128 * 64];
  __shared__ __align__(16) f16 Bs[128 * 64];
  const int tid = threadIdx.x;
  const int w = tid >> 6, l = tid & 63;
  const int wm = (w >> 1) * 64, wn = (w & 1) * 64;
  const int quad = l >> 4, lo = l & 15;
  // Staging: chunk c8 covers rows [c8*8,c8*8+8); lane l owns LDS slot l; its
  // global granule is (row rl=l>>3, col cg=(l&7)^rl)  -> XOR-swizzled layout.
  const int rl = l >> 3;
  const int scol = ((l & 7) ^ rl) * 8;
  // Fragment read: element (r, granule c) lives at r*64 + (c^(r&7))*8.
  const int swz = (quad ^ (lo & 3)) * 8;
  const int ks0 = ((lo >> 2) & 1) * 32;

  const f16* arow[4];
  const f16* brow[4];
#pragma unroll
  for (int r = 0; r < 4; ++r) {
    const int c8 = r * 4 + w;
    const int row = c8 * 8 + rl;
    if (selrow) {
      const int gr = m0 + row;
      arow[r] = (gr < cnt) ? (A + (long)selrow[gr] * lda + scol) : (zrow + scol);
    } else {
      arow[r] = A + (long)(m0 + row) * lda + scol;
    }
    brow[r] = B + (long)(n0 + row) * ldb + scol;
  }

  f32x4 acc[4][4] = {};
  for (int kk = 0; kk < K; kk += 64) {
#pragma unroll
    for (int r = 0; r < 4; ++r) {
      const int c8 = r * 4 + w;
      gld16(arow[r] + kk, &As[c8 * 512]);
      gld16(brow[r] + kk, &Bs[c8 * 512]);
    }
    __syncthreads();
#pragma unroll
    for (int ks = 0; ks < 2; ++ks) {
      const int kso = ks ? (32 - ks0) : ks0;
      f16x8 af[4], bf[4];
#pragma unroll
      for (int i = 0; i < 4; ++i)
        af[i] = *(const f16x8*)&As[(wm + i * 16 + lo) * 64 + swz + kso];
#pragma unroll
      for (int j = 0; j < 4; ++j)
        bf[j] = *(const f16x8*)&Bs[(wn + j * 16 + lo) * 64 + swz + kso];
#pragma unroll
      for (int i = 0; i < 4; ++i)
#pragma unroll
        for (int j = 0; j < 4; ++j)
          acc[i][j] = __builtin_amdgcn_mfma_f32_16x16x32_f16(af[i], bf[j],
                                                             acc[i][j], 0, 0, 0);
    }
    __syncthreads();
  }
  // Epilogue: C/D layout col=lane&15, row=quad*4+reg.
#pragma unroll
  for (int i = 0; i < 4; ++i) {
    const int rowb = m0 + wm + i * 16 + quad * 4;
#pragma unroll
    for (int j = 0; j < 4; ++j) {
      const int col = n0 + wn + j * 16 + lo;
      float bv = 0.f;
      if (bias1) bv = (col < nb1) ? bias1[col] : bias2[col - nb1];
#pragma unroll
      for (int r = 0; r < 4; ++r)
        C[(long)(rowb + r) * ldc + col] = (OutT)(acc[i][j][r] * scale + bv);
    }
  }
}

// ---------------------------------------------------------------- L1 prep
// Blocks [0,11263]: cast x (8M f32) then Wq|Wk|Wv (1M each) -> xh, Wh.
// Block 11264: zero zrow. Blocks 11265..11268: mask scan for batch b.
__global__ LB256 void prep(const float* __restrict__ x, const float* __restrict__ wq,
                           const float* __restrict__ wk, const float* __restrict__ wv,
                           const void* __restrict__ maskp, f16* __restrict__ xh,
                           f16* __restrict__ wh, f16* __restrict__ zrow,
                           int* __restrict__ sel, int* __restrict__ counts,
                           int* __restrict__ npad) {
  const int blk = blockIdx.x;
  const int t = threadIdx.x;
  if (blk < 11264) {
    long i = ((long)blk * 256 + t) * 4;
    const float* src;
    f16* dst;
    if (i < 8388608L) {
      src = x + i;
      dst = xh + i;
    } else {
      long j = i - 8388608L;
      int which = (int)(j >> 20);
      const float* ws = which == 0 ? wq : (which == 1 ? wk : wv);
      src = ws + (j & 1048575L);
      dst = wh + j;
    }
    float4 v = *(const float4*)src;
    f16x4 o;
    o[0] = (f16)v.x; o[1] = (f16)v.y; o[2] = (f16)v.z; o[3] = (f16)v.w;
    *(f16x4*)dst = o;
  } else if (blk == 11264) {
    *(f16x4*)(zrow + t * 4) = (f16x4){0, 0, 0, 0};
  } else {
    const int b = blk - 11265;
    __shared__ int bad;
    __shared__ int s[256];
    if (t == 0) bad = 0;
    __syncthreads();
    const int* mi = (const int*)maskp;
    int loc = 0;
    for (int i = t; i < 2048; i += 256)
      if ((unsigned)mi[i] > 1u) loc = 1;  // byte-packed bools look like big ints
    if (loc) atomicOr(&bad, 1);
    __syncthreads();
    const bool bytemode = bad != 0;
    int m[8];
    if (bytemode) {
      const unsigned char* p = (const unsigned char*)maskp + b * 2048 + t * 8;
#pragma unroll
      for (int e = 0; e < 8; ++e) m[e] = p[e] != 0;
    } else {
      const int* p = mi + b * 2048 + t * 8;
#pragma unroll
      for (int e = 0; e < 8; ++e) m[e] = p[e] != 0;
    }
    int local = 0;
#pragma unroll
    for (int e = 0; e < 8; ++e) local += m[e];
    s[t] = local;
    __syncthreads();
    for (int off = 1; off < 256; off <<= 1) {
      int v = (t >= off) ? s[t - off] : 0;
      __syncthreads();
      s[t] += v;
      __syncthreads();
    }
    int offp = s[t] - local;
#pragma unroll
    for (int e = 0; e < 8; ++e)
      if (m[e]) sel[b * 2048 + offp++] = t * 8 + e;
    if (t == 0) {
      counts[b] = s[255];
      npad[b] = ((s[255] + 127) >> 7) << 7;
    }
  }
}

// ---------------------------------------------------------------- L2 Q + KV mega-GEMM
// z<4: [Kc|Vc](b=z) = gather(xh)@[Wk|Wv]^T + [bk|bv], M=npad[z], N=2048, K=1024.
// z>=4: Q = xh@Wq^T + bq, M=8192 (zz=z-4 covers half), N=1024, K=1024.
__global__ __launch_bounds__(256, 4) void qkv_gemm(
    const f16* __restrict__ xh, const f16* __restrict__ Wh, f16* __restrict__ Qb,
    f16* __restrict__ KVc, const float* __restrict__ bq,
    const float* __restrict__ bk, const float* __restrict__ bv,
    const int* __restrict__ sel, const int* __restrict__ counts,
    const int* __restrict__ npad, const f16* __restrict__ zrow) {
  const int z = blockIdx.z;
  if (z < 4) {
    const int m0 = blockIdx.y * 128;
    if (m0 >= npad[z]) return;
    gemm_body<f16>(xh + (long)z * 2048 * 1024, 1024, sel + z * 2048, counts[z],
                   zrow, Wh + 1048576, 1024, KVc + (long)z * 2048 * 2048, 2048,
                   bk, bv, 1024, 1.0f, 1024, m0, blockIdx.x * 128);
  } else {
    const int zz = z - 4;
    const int tix = blockIdx.y * 16 + blockIdx.x;  // 0..255
    const int m0 = ((tix >> 3) + zz * 32) * 128;
    const int n0 = (tix & 7) * 128;
    gemm_body<f16>(xh, 1024, nullptr, 0, nullptr, Wh, 1024, Qb, 1024,
                   bq, bq, 1 << 30, 1.0f, 1024, m0, n0);
  }
}

// ---------------------------------------------------------------- L3 scores + V-transpose
// z<4: S(b=z) = (Q Kc^T)/32, M=2048, N=npad[z], K=1024.
// z=4..11: transpose slices: Vtc[b][d][s'] = KVc[b][s'][1024+d], 64x64 per block.
__global__ __launch_bounds__(256, 4) void scores_transpose(
    const f16* __restrict__ Qb, const f16* __restrict__ KVc, f16* __restrict__ Sbuf,
    f16* __restrict__ Vtc, const int* __restrict__ npad) {
  const int z = blockIdx.z;
  if (z < 4) {
    const int n0 = blockIdx.x * 128;
    if (n0 >= npad[z]) return;
    gemm_body<f16>(Qb + (long)z * 2048 * 1024, 1024, nullptr, 0, nullptr,
                   KVc + (long)z * 2048 * 2048, 2048, Sbuf + (long)z * 2048 * 2048,
                   2048, nullptr, nullptr, 0, 0.03125f, 1024, blockIdx.y * 128, n0);
  } else {
    const int s4 = z - 4;          // slice 0..7
    const int b = s4 >> 1;
    const int half = s4 & 1;
    const int d0 = blockIdx.x * 64;
    const int s0 = (blockIdx.y + half * 16) * 64;
    if (s0 >= npad[b]) return;
    __shared__ f16 tt[32][33];
    const int tx = threadIdx.x & 31;
    const int ty = threadIdx.x >> 5;  // 0..7
#pragma unroll
    for (int st = 0; st < 4; ++st) {
      const int dd = d0 + (st & 1) * 32;
      const int ss = s0 + (st >> 1) * 32;
      const f16* src = KVc + ((long)b * 2048 + ss) * 2048 + 1024 + dd;
#pragma unroll
      for (int i = 0; i < 4; ++i)
        tt[ty + i * 8][tx] = src[(long)(ty + i * 8) * 2048 + tx];
      __syncthreads();
      f16* dst = Vtc + ((long)b * 1024 + dd) * 2048 + ss;
#pragma unroll
      for (int i = 0; i < 4; ++i)
        dst[(long)(ty + i * 8) * 2048 + tx] = tt[tx][ty + i * 8];
      __syncthreads();
    }
  }
}

// ---------------------------------------------------------------- L4 softmax (compacted)
__global__ LB256 void softmax_c(f16* __restrict__ S, const int* __restrict__ counts,
                                const int* __restrict__ npad) {
  __shared__ float red[4];
  const long r = blockIdx.x;
  const int b = (int)(r >> 11);
  const int nv = counts[b], np = npad[b];
  f16* row = S + r * 2048;
  const int t = threadIdx.x;
  const bool act = (t * 8) < np;

  float v[8];
  float mx = -3.0e38f;
  if (act) {
    f16x8 sv = *(const f16x8*)(row + t * 8);
#pragma unroll
    for (int e = 0; e < 8; ++e) {
      float s = (t * 8 + e < nv) ? (float)sv[e] : -3.0e38f;
      v[e] = s;
      mx = fmaxf(mx, s);
    }
  } else {
#pragma unroll
    for (int e = 0; e < 8; ++e) v[e] = -3.0e38f;
  }
#pragma unroll
  for (int off = 32; off > 0; off >>= 1) mx = fmaxf(mx, __shfl_xor(mx, off, 64));
  if ((t & 63) == 0) red[t >> 6] = mx;
  __syncthreads();
  mx = fmaxf(fmaxf(red[0], red[1]), fmaxf(red[2], red[3]));
  __syncthreads();

  float e[8];
  float sum = 0.f;
#pragma unroll
  for (int it = 0; it < 8; ++it) {
    float ev = (v[it] <= -1.0e38f) ? 0.f : __expf(v[it] - mx);
    e[it] = ev;
    sum += ev;
  }
#pragma unroll
  for (int off = 32; off > 0; off >>= 1) sum += __shfl_xor(sum, off, 64);
  if ((t & 63) == 0) red[t >> 6] = sum;
  __syncthreads();
  sum = red[0] + red[1] + red[2] + red[3];
  if (act) {
    const float inv = 1.f / sum;
    f16x8 ov;
#pragma unroll
    for (int it = 0; it < 8; ++it) ov[it] = (f16)(e[it] * inv);
    *(f16x8*)(row + t * 8) = ov;
  }
}

// ---------------------------------------------------------------- L5 PV GEMM
__global__ __launch_bounds__(256, 4) void pv_gemm(
    const f16* __restrict__ Sbuf, const f16* __restrict__ Vtc,
    float* __restrict__ out, const int* __restrict__ npad) {
  const int z = blockIdx.z;
  gemm_body<float>(Sbuf + (long)z * 2048 * 2048, 2048, nullptr, 0, nullptr,
                   Vtc + (long)z * 1024 * 2048, 2048, out + (long)z * 2048 * 1024,
                   1024, nullptr, nullptr, 0, 1.0f, npad[z], blockIdx.y * 128,
                   blockIdx.x * 128);
}

// ---------------------------------------------------------------- launch
extern "C" void kernel_launch(void* const* d_in, const int* in_sizes, int n_in,
                              void* d_out, int out_size, void* d_ws, size_t ws_size,
                              hipStream_t stream) {
  const float* x = (const float*)d_in[0];
  const void* mask = d_in[1];
  const float* Wq = (const float*)d_in[2];
  const float* bq = (const float*)d_in[3];
  const float* Wk = (const float*)d_in[4];
  const float* bk = (const float*)d_in[5];
  const float* Wv = (const float*)d_in[6];
  const float* bv = (const float*)d_in[7];
  float* out = (float*)d_out;

  // Workspace (f16 elems), ~102 MB. Sbuf aliases xh + next 16MB (xh dead by L3).
  f16* xh = (f16*)d_ws;              // 8M
  f16* Sbuf = xh;                    // 16M (alias, spans [0,32MB))
  f16* Wh = xh + 16777216;           // 3M  [Wq|Wk|Wv]
  f16* Qb = Wh + 3145728;            // 8M
  f16* KVc = Qb + 8388608;           // 16M [K|V] compacted
  f16* Vtc = KVc + 16777216;         // 8M
  int* sel = (int*)(Vtc + 8388608);  // 8192
  int* counts = sel + 8192;          // 4
  int* npad = counts + 4;            // 4
  f16* zrow = (f16*)(npad + 4);      // 1024 zeros

  prep<<<11269, 256, 0, stream>>>(x, Wq, Wk, Wv, mask, xh, Wh, zrow, sel, counts,
                                  npad);
  qkv_gemm<<<dim3(16, 16, 6), 256, 0, stream>>>(xh, Wh, Qb, KVc, bq, bk, bv, sel,
                                                counts, npad, zrow);
  scores_transpose<<<dim3(16, 16, 12), 256, 0, stream>>>(Qb, KVc, Sbuf, Vtc, npad);
  softmax_c<<<8192, 256, 0, stream>>>(Sbuf, counts, npad);
  pv_gemm<<<dim3(8, 16, 4), 256, 0, stream>>>(Sbuf, Vtc, out, npad);
}

// Round 5
// 253.797 us; speedup vs baseline: 1.1712x; 1.1712x over previous
//
#include <hip/hip_runtime.h>

// Fused attention with masked-key compaction, 8 dispatches (R3-proven structure;
// R4's fusion+indirect-gather regressed ~2x on HBM traffic and was reverted):
//  L1 prep:    cast x,W -> f16; per-batch mask scan (sel/counts/npad)
//  L2 gather:  xc[b][s'] = xh[b][sel[s']] (pad rows zeroed)
//  L3 q_gemm:  Q = x@Wq^T + bq                  M=8192,N=1024,K=1024
//  L4 k_gemm:  Kc = xc@Wk^T + bk                M=npad, N=1024,K=1024 (per batch)
//  L5 vt_gemm: Vt = Wv@xc^T + bv[row]           M=1024, N=npad,K=1024 (direct V^T!)
//  L6 scores:  S = (Q Kc^T)/32                  M=2048, N=npad,K=1024
//  L7 softmax: compacted rows (cols>=counts -> -inf; pad cols -> 0)
//  L8 pv:      O = P @ Vt^T (K=npad), fp32 out  M=2048, N=1024
// GEMM core: 128x128 tile, 4 waves, 4x4 16x16x32 f16 MFMA, BK=64, global_load_lds
// w=16, XOR-swizzled LDS (SQ_LDS_BANK_CONFLICT=0 verified R2), contiguous staging.

typedef _Float16 f16;
typedef _Float16 f16x4 __attribute__((ext_vector_type(4)));
typedef _Float16 f16x8 __attribute__((ext_vector_type(8)));
typedef float f32x4 __attribute__((ext_vector_type(4)));

#define LB256 __launch_bounds__(256)

__device__ __forceinline__ void gld16(const void* gp, void* lp) {
  __builtin_amdgcn_global_load_lds(
      (__attribute__((address_space(1))) void*)(gp),
      (__attribute__((address_space(3))) void*)(lp),
      16, 0, 0);
}

// ---------------------------------------------------------------- GEMM body
// C[m,n] = scale * sum_k A[m,k]*B[n,k] + bias. bias_row=0: bias(col) via
// bias1/bias2 split at nb1; bias_row=1: bias1(row).
template <typename OutT>
__device__ __forceinline__ void gemm_body(
    const f16* __restrict__ A, int lda, const f16* __restrict__ B, int ldb,
    OutT* __restrict__ C, int ldc,
    const float* __restrict__ bias1, const float* __restrict__ bias2, int nb1,
    int bias_row, float scale, int K, int m0, int n0) {
  __shared__ __align__(16) f16 As[128 * 64];
  __shared__ __align__(16) f16 Bs[128 * 64];
  const int tid = threadIdx.x;
  const int w = tid >> 6, l = tid & 63;
  const int wm = (w >> 1) * 64, wn = (w & 1) * 64;
  const int quad = l >> 4, lo = l & 15;
  // Staging: chunk c8 covers rows [c8*8,c8*8+8); lane l owns LDS slot l; its
  // global granule is (row rl=l>>3, col cg=(l&7)^rl) -> XOR-swizzled layout.
  const int rl = l >> 3;
  const int scol = ((l & 7) ^ rl) * 8;
  // Fragment read: element (r, granule c) lives at r*64 + (c^(r&7))*8.
  const int swz = (quad ^ (lo & 3)) * 8;
  const int ks0 = ((lo >> 2) & 1) * 32;

  f32x4 acc[4][4] = {};
  for (int kk = 0; kk < K; kk += 64) {
#pragma unroll
    for (int r = 0; r < 4; ++r) {
      const int c8 = r * 4 + w;
      const int row = c8 * 8 + rl;
      gld16(A + (long)(m0 + row) * lda + kk + scol, &As[c8 * 512]);
      gld16(B + (long)(n0 + row) * ldb + kk + scol, &Bs[c8 * 512]);
    }
    __syncthreads();
#pragma unroll
    for (int ks = 0; ks < 2; ++ks) {
      const int kso = ks ? (32 - ks0) : ks0;
      f16x8 af[4], bf[4];
#pragma unroll
      for (int i = 0; i < 4; ++i)
        af[i] = *(const f16x8*)&As[(wm + i * 16 + lo) * 64 + swz + kso];
#pragma unroll
      for (int j = 0; j < 4; ++j)
        bf[j] = *(const f16x8*)&Bs[(wn + j * 16 + lo) * 64 + swz + kso];
#pragma unroll
      for (int i = 0; i < 4; ++i)
#pragma unroll
        for (int j = 0; j < 4; ++j)
          acc[i][j] = __builtin_amdgcn_mfma_f32_16x16x32_f16(af[i], bf[j],
                                                             acc[i][j], 0, 0, 0);
    }
    __syncthreads();
  }
  // Epilogue: C/D layout col=lane&15, row=quad*4+reg.
#pragma unroll
  for (int i = 0; i < 4; ++i) {
    const int rowb = m0 + wm + i * 16 + quad * 4;
#pragma unroll
    for (int j = 0; j < 4; ++j) {
      const int col = n0 + wn + j * 16 + lo;
      float bc = 0.f;
      if (bias1 && !bias_row) bc = (col < nb1) ? bias1[col] : bias2[col - nb1];
#pragma unroll
      for (int r = 0; r < 4; ++r) {
        float bv = bias_row ? bias1[rowb + r] : bc;
        C[(long)(rowb + r) * ldc + col] = (OutT)(acc[i][j][r] * scale + bv);
      }
    }
  }
}

// ---------------------------------------------------------------- L1 prep
// Blocks [0,11263]: cast x (8M f32) then Wq|Wk|Wv (1M each) -> xh, Wh.
// Blocks 11264..11267: mask scan for batch b (sel/counts/npad).
__global__ LB256 void prep(const float* __restrict__ x, const float* __restrict__ wq,
                           const float* __restrict__ wk, const float* __restrict__ wv,
                           const void* __restrict__ maskp, f16* __restrict__ xh,
                           f16* __restrict__ wh, int* __restrict__ sel,
                           int* __restrict__ counts, int* __restrict__ npad) {
  const int blk = blockIdx.x;
  const int t = threadIdx.x;
  if (blk < 11264) {
    long i = ((long)blk * 256 + t) * 4;
    const float* src;
    f16* dst;
    if (i < 8388608L) {
      src = x + i;
      dst = xh + i;
    } else {
      long j = i - 8388608L;
      int which = (int)(j >> 20);
      const float* ws = which == 0 ? wq : (which == 1 ? wk : wv);
      src = ws + (j & 1048575L);
      dst = wh + j;
    }
    float4 v = *(const float4*)src;
    f16x4 o;
    o[0] = (f16)v.x; o[1] = (f16)v.y; o[2] = (f16)v.z; o[3] = (f16)v.w;
    *(f16x4*)dst = o;
  } else {
    const int b = blk - 11264;
    __shared__ int bad;
    __shared__ int s[256];
    if (t == 0) bad = 0;
    __syncthreads();
    const int* mi = (const int*)maskp;
    int loc = 0;
    for (int i = t; i < 2048; i += 256)
      if ((unsigned)mi[i] > 1u) loc = 1;  // byte-packed bools look like big ints
    if (loc) atomicOr(&bad, 1);
    __syncthreads();
    const bool bytemode = bad != 0;
    int m[8];
    if (bytemode) {
      const unsigned char* p = (const unsigned char*)maskp + b * 2048 + t * 8;
#pragma unroll
      for (int e = 0; e < 8; ++e) m[e] = p[e] != 0;
    } else {
      const int* p = mi + b * 2048 + t * 8;
#pragma unroll
      for (int e = 0; e < 8; ++e) m[e] = p[e] != 0;
    }
    int local = 0;
#pragma unroll
    for (int e = 0; e < 8; ++e) local += m[e];
    s[t] = local;
    __syncthreads();
    for (int off = 1; off < 256; off <<= 1) {
      int v = (t >= off) ? s[t - off] : 0;
      __syncthreads();
      s[t] += v;
      __syncthreads();
    }
    int offp = s[t] - local;
#pragma unroll
    for (int e = 0; e < 8; ++e)
      if (m[e]) sel[b * 2048 + offp++] = t * 8 + e;
    if (t == 0) {
      counts[b] = s[255];
      npad[b] = ((s[255] + 127) >> 7) << 7;
    }
  }
}

// ---------------------------------------------------------------- L2 gather
// xc[b][s'] = xh[b][sel[s']] for s'<counts; zeros for [counts,npad). 4 rows/block.
__global__ LB256 void gather_x(const f16* __restrict__ xh, const int* __restrict__ sel,
                               const int* __restrict__ counts,
                               const int* __restrict__ npad, f16* __restrict__ xc) {
  const int b = blockIdx.y;
  const int np = npad[b], cnt = counts[b];
  const int t = threadIdx.x;
#pragma unroll
  for (int i = 0; i < 4; ++i) {
    const int sp = blockIdx.x * 4 + i;
    if (sp >= np) continue;
    f16* dst = xc + ((long)b * 2048 + sp) * 1024;
    if (sp >= cnt) {
      *(f16x4*)(dst + t * 4) = (f16x4){0, 0, 0, 0};
    } else {
      const f16* src = xh + ((long)b * 2048 + sel[b * 2048 + sp]) * 1024;
      *(f16x4*)(dst + t * 4) = *(const f16x4*)(src + t * 4);
    }
  }
}

// ---------------------------------------------------------------- L3 Q GEMM
__global__ __launch_bounds__(256, 4) void q_gemm(
    const f16* __restrict__ xh, const f16* __restrict__ Wh, f16* __restrict__ Qb,
    const float* __restrict__ bq) {
  gemm_body<f16>(xh, 1024, Wh, 1024, Qb, 1024, bq, bq, 1 << 30, 0, 1.0f, 1024,
                 blockIdx.y * 128, blockIdx.x * 128);
}

// ---------------------------------------------------------------- L4 K GEMM (compacted rows)
__global__ __launch_bounds__(256, 4) void k_gemm(
    const f16* __restrict__ xc, const f16* __restrict__ Wh, f16* __restrict__ Kc,
    const float* __restrict__ bk, const int* __restrict__ npad) {
  const int z = blockIdx.z;
  const int m0 = blockIdx.y * 128;
  if (m0 >= npad[z]) return;
  gemm_body<f16>(xc + (long)z * 2048 * 1024, 1024, Wh + 1048576, 1024,
                 Kc + (long)z * 2048 * 1024, 1024, bk, bk, 1 << 30, 0, 1.0f, 1024,
                 m0, blockIdx.x * 128);
}

// ---------------------------------------------------------------- L5 V^T GEMM
// Vt[b][d][s'] = sum_k Wv[d,k]*xc[b][s',k] + bv[d]  (bias by row; pad cols get
// bv[d] but are multiplied by P=0 downstream).
__global__ __launch_bounds__(256, 4) void vt_gemm(
    const f16* __restrict__ Wh, const f16* __restrict__ xc, f16* __restrict__ Vt,
    const float* __restrict__ bv, const int* __restrict__ npad) {
  const int z = blockIdx.z;
  const int n0 = blockIdx.x * 128;
  if (n0 >= npad[z]) return;
  gemm_body<f16>(Wh + 2097152, 1024, xc + (long)z * 2048 * 1024, 1024,
                 Vt + (long)z * 1024 * 2048, 2048, bv, bv, 0, 1, 1.0f, 1024,
                 blockIdx.y * 128, n0);
}

// ---------------------------------------------------------------- L6 scores GEMM
__global__ __launch_bounds__(256, 4) void s_gemm(
    const f16* __restrict__ Qb, const f16* __restrict__ Kc, f16* __restrict__ Sbuf,
    const int* __restrict__ npad) {
  const int z = blockIdx.z;
  const int n0 = blockIdx.x * 128;
  if (n0 >= npad[z]) return;
  gemm_body<f16>(Qb + (long)z * 2048 * 1024, 1024, Kc + (long)z * 2048 * 1024, 1024,
                 Sbuf + (long)z * 2048 * 2048, 2048, nullptr, nullptr, 0, 0,
                 0.03125f, 1024, blockIdx.y * 128, n0);
}

// ---------------------------------------------------------------- L7 softmax (compacted)
__global__ LB256 void softmax_c(f16* __restrict__ S, const int* __restrict__ counts,
                                const int* __restrict__ npad) {
  __shared__ float red[4];
  const long r = blockIdx.x;
  const int b = (int)(r >> 11);
  const int nv = counts[b], np = npad[b];
  f16* row = S + r * 2048;
  const int t = threadIdx.x;
  const bool act = (t * 8) < np;

  float v[8];
  float mx = -3.0e38f;
  if (act) {
    f16x8 sv = *(const f16x8*)(row + t * 8);
#pragma unroll
    for (int e = 0; e < 8; ++e) {
      float s = (t * 8 + e < nv) ? (float)sv[e] : -3.0e38f;
      v[e] = s;
      mx = fmaxf(mx, s);
    }
  } else {
#pragma unroll
    for (int e = 0; e < 8; ++e) v[e] = -3.0e38f;
  }
#pragma unroll
  for (int off = 32; off > 0; off >>= 1) mx = fmaxf(mx, __shfl_xor(mx, off, 64));
  if ((t & 63) == 0) red[t >> 6] = mx;
  __syncthreads();
  mx = fmaxf(fmaxf(red[0], red[1]), fmaxf(red[2], red[3]));
  __syncthreads();

  float e[8];
  float sum = 0.f;
#pragma unroll
  for (int it = 0; it < 8; ++it) {
    float ev = (v[it] <= -1.0e38f) ? 0.f : __expf(v[it] - mx);
    e[it] = ev;
    sum += ev;
  }
#pragma unroll
  for (int off = 32; off > 0; off >>= 1) sum += __shfl_xor(sum, off, 64);
  if ((t & 63) == 0) red[t >> 6] = sum;
  __syncthreads();
  sum = red[0] + red[1] + red[2] + red[3];
  if (act) {
    const float inv = 1.f / sum;
    f16x8 ov;
#pragma unroll
    for (int it = 0; it < 8; ++it) ov[it] = (f16)(e[it] * inv);
    *(f16x8*)(row + t * 8) = ov;
  }
}

// ---------------------------------------------------------------- L8 PV GEMM
__global__ __launch_bounds__(256, 4) void pv_gemm(
    const f16* __restrict__ Sbuf, const f16* __restrict__ Vt,
    float* __restrict__ out, const int* __restrict__ npad) {
  const int z = blockIdx.z;
  gemm_body<float>(Sbuf + (long)z * 2048 * 2048, 2048, Vt + (long)z * 1024 * 2048,
                   2048, out + (long)z * 2048 * 1024, 1024, nullptr, nullptr, 0, 0,
                   1.0f, npad[z], blockIdx.y * 128, blockIdx.x * 128);
}

// ---------------------------------------------------------------- launch
extern "C" void kernel_launch(void* const* d_in, const int* in_sizes, int n_in,
                              void* d_out, int out_size, void* d_ws, size_t ws_size,
                              hipStream_t stream) {
  const float* x = (const float*)d_in[0];
  const void* mask = d_in[1];
  const float* Wq = (const float*)d_in[2];
  const float* bq = (const float*)d_in[3];
  const float* Wk = (const float*)d_in[4];
  const float* bk = (const float*)d_in[5];
  const float* Wv = (const float*)d_in[6];
  const float* bv = (const float*)d_in[7];
  float* out = (float*)d_out;

  // Workspace (f16 elems), ~86 MB. Sbuf (32 MB) aliases xh+xc (dead before L6).
  f16* xh = (f16*)d_ws;              // 8M  [0,16MB)
  f16* xc = xh + 8388608;            // 8M  [16,32)
  f16* Sbuf = xh;                    // 16M [0,32) alias
  f16* Wh = xc + 8388608;            // 3M  [32,38)  [Wq|Wk|Wv]
  f16* Qb = Wh + 3145728;            // 8M  [38,54)
  f16* Kc = Qb + 8388608;            // 8M  [54,70)
  f16* Vt = Kc + 8388608;            // 8M  [70,86)
  int* sel = (int*)(Vt + 8388608);   // 8192
  int* counts = sel + 8192;          // 4
  int* npad = counts + 4;            // 4

  prep<<<11268, 256, 0, stream>>>(x, Wq, Wk, Wv, mask, xh, Wh, sel, counts, npad);
  gather_x<<<dim3(512, 4), 256, 0, stream>>>(xh, sel, counts, npad, xc);
  q_gemm<<<dim3(8, 64), 256, 0, stream>>>(xh, Wh, Qb, bq);
  k_gemm<<<dim3(8, 16, 4), 256, 0, stream>>>(xc, Wh, Kc, bk, npad);
  vt_gemm<<<dim3(16, 8, 4), 256, 0, stream>>>(Wh, xc, Vt, bv, npad);
  s_gemm<<<dim3(16, 16, 4), 256, 0, stream>>>(Qb, Kc, Sbuf, npad);
  softmax_c<<<8192, 256, 0, stream>>>(Sbuf, counts, npad);
  pv_gemm<<<dim3(8, 16, 4), 256, 0, stream>>>(Sbuf, Vt, out, npad);
}

// Round 6
// 237.970 us; speedup vs baseline: 1.2491x; 1.0665x over previous
//
#include <hip/hip_runtime.h>

// Fused attention with masked-key compaction, 6 dispatches:
//  L1 prep:    cast x,W -> f16; per-batch mask scan (sel/counts/npad)
//  L2 gather:  xc[b][s'] = xh[b][sel[s']] (pad rows zeroed)
//  L3 qk:      Q = x@Wq^T+bq (512 tiles)  ||  Kc = xc@Wk^T+bk (<=512 tiles, npad-gated)
//  L4 svt:     S = (Q Kc^T)/32 (npad-gated) || Vt = Wv@xc^T+bv[row] (direct V^T)
//  L5 softmax: compacted rows (cols>=counts -> -inf; pad cols -> 0)
//  L6 pv:      O = P @ Vt^T (K=npad), fp32 out
// Independent GEMMs co-dispatched in one launch for CU packing (each alone is
// only 1-2 blocks/CU; the 128-tile structure needs ~4/CU for its ~839 TF rate).
// GEMM core: 128x128 tile, 4 waves, 4x4 16x16x32 f16 MFMA, BK=64, global_load_lds
// w=16, XOR-swizzled LDS (SQ_LDS_BANK_CONFLICT=0 verified R2), contiguous staging.

typedef _Float16 f16;
typedef _Float16 f16x4 __attribute__((ext_vector_type(4)));
typedef _Float16 f16x8 __attribute__((ext_vector_type(8)));
typedef float f32x4 __attribute__((ext_vector_type(4)));

#define LB256 __launch_bounds__(256)

__device__ __forceinline__ void gld16(const void* gp, void* lp) {
  __builtin_amdgcn_global_load_lds(
      (__attribute__((address_space(1))) void*)(gp),
      (__attribute__((address_space(3))) void*)(lp),
      16, 0, 0);
}

// ---------------------------------------------------------------- GEMM body
// C[m,n] = scale * sum_k A[m,k]*B[n,k] + bias. bias_row=0: bias(col) via
// bias1/bias2 split at nb1; bias_row=1: bias1(row).
template <typename OutT>
__device__ __forceinline__ void gemm_body(
    const f16* __restrict__ A, int lda, const f16* __restrict__ B, int ldb,
    OutT* __restrict__ C, int ldc,
    const float* __restrict__ bias1, const float* __restrict__ bias2, int nb1,
    int bias_row, float scale, int K, int m0, int n0) {
  __shared__ __align__(16) f16 As[128 * 64];
  __shared__ __align__(16) f16 Bs[128 * 64];
  const int tid = threadIdx.x;
  const int w = tid >> 6, l = tid & 63;
  const int wm = (w >> 1) * 64, wn = (w & 1) * 64;
  const int quad = l >> 4, lo = l & 15;
  // Staging: chunk c8 covers rows [c8*8,c8*8+8); lane l owns LDS slot l; its
  // global granule is (row rl=l>>3, col cg=(l&7)^rl) -> XOR-swizzled layout.
  const int rl = l >> 3;
  const int scol = ((l & 7) ^ rl) * 8;
  // Fragment read: element (r, granule c) lives at r*64 + (c^(r&7))*8.
  const int swz = (quad ^ (lo & 3)) * 8;
  const int ks0 = ((lo >> 2) & 1) * 32;

  f32x4 acc[4][4] = {};
  for (int kk = 0; kk < K; kk += 64) {
#pragma unroll
    for (int r = 0; r < 4; ++r) {
      const int c8 = r * 4 + w;
      const int row = c8 * 8 + rl;
      gld16(A + (long)(m0 + row) * lda + kk + scol, &As[c8 * 512]);
      gld16(B + (long)(n0 + row) * ldb + kk + scol, &Bs[c8 * 512]);
    }
    __syncthreads();
#pragma unroll
    for (int ks = 0; ks < 2; ++ks) {
      const int kso = ks ? (32 - ks0) : ks0;
      f16x8 af[4], bf[4];
#pragma unroll
      for (int i = 0; i < 4; ++i)
        af[i] = *(const f16x8*)&As[(wm + i * 16 + lo) * 64 + swz + kso];
#pragma unroll
      for (int j = 0; j < 4; ++j)
        bf[j] = *(const f16x8*)&Bs[(wn + j * 16 + lo) * 64 + swz + kso];
#pragma unroll
      for (int i = 0; i < 4; ++i)
#pragma unroll
        for (int j = 0; j < 4; ++j)
          acc[i][j] = __builtin_amdgcn_mfma_f32_16x16x32_f16(af[i], bf[j],
                                                             acc[i][j], 0, 0, 0);
    }
    __syncthreads();
  }
  // Epilogue: C/D layout col=lane&15, row=quad*4+reg.
#pragma unroll
  for (int i = 0; i < 4; ++i) {
    const int rowb = m0 + wm + i * 16 + quad * 4;
#pragma unroll
    for (int j = 0; j < 4; ++j) {
      const int col = n0 + wn + j * 16 + lo;
      float bc = 0.f;
      if (bias1 && !bias_row) bc = (col < nb1) ? bias1[col] : bias2[col - nb1];
#pragma unroll
      for (int r = 0; r < 4; ++r) {
        float bv = bias_row ? bias1[rowb + r] : bc;
        C[(long)(rowb + r) * ldc + col] = (OutT)(acc[i][j][r] * scale + bv);
      }
    }
  }
}

// ---------------------------------------------------------------- L1 prep
// Blocks [0,11263]: cast x (8M f32) then Wq|Wk|Wv (1M each) -> xh, Wh.
// Blocks 11264..11267: mask scan for batch b (sel/counts/npad).
__global__ LB256 void prep(const float* __restrict__ x, const float* __restrict__ wq,
                           const float* __restrict__ wk, const float* __restrict__ wv,
                           const void* __restrict__ maskp, f16* __restrict__ xh,
                           f16* __restrict__ wh, int* __restrict__ sel,
                           int* __restrict__ counts, int* __restrict__ npad) {
  const int blk = blockIdx.x;
  const int t = threadIdx.x;
  if (blk < 11264) {
    long i = ((long)blk * 256 + t) * 4;
    const float* src;
    f16* dst;
    if (i < 8388608L) {
      src = x + i;
      dst = xh + i;
    } else {
      long j = i - 8388608L;
      int which = (int)(j >> 20);
      const float* ws = which == 0 ? wq : (which == 1 ? wk : wv);
      src = ws + (j & 1048575L);
      dst = wh + j;
    }
    float4 v = *(const float4*)src;
    f16x4 o;
    o[0] = (f16)v.x; o[1] = (f16)v.y; o[2] = (f16)v.z; o[3] = (f16)v.w;
    *(f16x4*)dst = o;
  } else {
    const int b = blk - 11264;
    __shared__ int bad;
    __shared__ int s[256];
    if (t == 0) bad = 0;
    __syncthreads();
    const int* mi = (const int*)maskp;
    int loc = 0;
    for (int i = t; i < 2048; i += 256)
      if ((unsigned)mi[i] > 1u) loc = 1;  // byte-packed bools look like big ints
    if (loc) atomicOr(&bad, 1);
    __syncthreads();
    const bool bytemode = bad != 0;
    int m[8];
    if (bytemode) {
      const unsigned char* p = (const unsigned char*)maskp + b * 2048 + t * 8;
#pragma unroll
      for (int e = 0; e < 8; ++e) m[e] = p[e] != 0;
    } else {
      const int* p = mi + b * 2048 + t * 8;
#pragma unroll
      for (int e = 0; e < 8; ++e) m[e] = p[e] != 0;
    }
    int local = 0;
#pragma unroll
    for (int e = 0; e < 8; ++e) local += m[e];
    s[t] = local;
    __syncthreads();
    for (int off = 1; off < 256; off <<= 1) {
      int v = (t >= off) ? s[t - off] : 0;
      __syncthreads();
      s[t] += v;
      __syncthreads();
    }
    int offp = s[t] - local;
#pragma unroll
    for (int e = 0; e < 8; ++e)
      if (m[e]) sel[b * 2048 + offp++] = t * 8 + e;
    if (t == 0) {
      counts[b] = s[255];
      npad[b] = ((s[255] + 127) >> 7) << 7;
    }
  }
}

// ---------------------------------------------------------------- L2 gather
__global__ LB256 void gather_x(const f16* __restrict__ xh, const int* __restrict__ sel,
                               const int* __restrict__ counts,
                               const int* __restrict__ npad, f16* __restrict__ xc) {
  const int b = blockIdx.y;
  const int np = npad[b], cnt = counts[b];
  const int t = threadIdx.x;
#pragma unroll
  for (int i = 0; i < 4; ++i) {
    const int sp = blockIdx.x * 4 + i;
    if (sp >= np) continue;
    f16* dst = xc + ((long)b * 2048 + sp) * 1024;
    if (sp >= cnt) {
      *(f16x4*)(dst + t * 4) = (f16x4){0, 0, 0, 0};
    } else {
      const f16* src = xh + ((long)b * 2048 + sel[b * 2048 + sp]) * 1024;
      *(f16x4*)(dst + t * 4) = *(const f16x4*)(src + t * 4);
    }
  }
}

// ---------------------------------------------------------------- L3 Q || K GEMM
// t<512:  Q tile: M=8192, N=1024, K=1024.
// t>=512: K tile u=t-512: z=u>>7, m-tile=(u&127)>>3, n-tile=u&7; M=npad[z].
__global__ __launch_bounds__(256, 4) void qk_gemm(
    const f16* __restrict__ xh, const f16* __restrict__ xc,
    const f16* __restrict__ Wh, f16* __restrict__ Qb, f16* __restrict__ Kc,
    const float* __restrict__ bq, const float* __restrict__ bk,
    const int* __restrict__ npad) {
  const int t = blockIdx.x;
  if (t < 512) {
    gemm_body<f16>(xh, 1024, Wh, 1024, Qb, 1024, bq, bq, 1 << 30, 0, 1.0f, 1024,
                   (t >> 3) * 128, (t & 7) * 128);
  } else {
    const int u = t - 512;
    const int z = u >> 7, rem = u & 127;
    const int m0 = (rem >> 3) * 128, n0 = (rem & 7) * 128;
    if (m0 >= npad[z]) return;
    gemm_body<f16>(xc + (long)z * 2048 * 1024, 1024, Wh + 1048576, 1024,
                   Kc + (long)z * 2048 * 1024, 1024, bk, bk, 1 << 30, 0, 1.0f,
                   1024, m0, n0);
  }
}

// ---------------------------------------------------------------- L4 S || V^T GEMM
// t<1024:  S tile: z=t>>8, m-tile=(t&255)>>4, n-tile=t&15; N=npad[z].
// t>=1024: Vt tile u: z=u>>7, m-tile=(u&127)>>4 (M=1024), n-tile=u&15 (N=npad).
__global__ __launch_bounds__(256, 4) void svt_gemm(
    const f16* __restrict__ Qb, const f16* __restrict__ Kc, f16* __restrict__ Sbuf,
    const f16* __restrict__ Wh, const f16* __restrict__ xc, f16* __restrict__ Vt,
    const float* __restrict__ bv, const int* __restrict__ npad) {
  const int t = blockIdx.x;
  if (t < 1024) {
    const int z = t >> 8, rem = t & 255;
    const int m0 = (rem >> 4) * 128, n0 = (rem & 15) * 128;
    if (n0 >= npad[z]) return;
    gemm_body<f16>(Qb + (long)z * 2048 * 1024, 1024, Kc + (long)z * 2048 * 1024,
                   1024, Sbuf + (long)z * 2048 * 2048, 2048, nullptr, nullptr, 0,
                   0, 0.03125f, 1024, m0, n0);
  } else {
    const int u = t - 1024;
    const int z = u >> 7, rem = u & 127;
    const int m0 = (rem >> 4) * 128, n0 = (rem & 15) * 128;
    if (n0 >= npad[z]) return;
    gemm_body<f16>(Wh + 2097152, 1024, xc + (long)z * 2048 * 1024, 1024,
                   Vt + (long)z * 1024 * 2048, 2048, bv, bv, 0, 1, 1.0f, 1024,
                   m0, n0);
  }
}

// ---------------------------------------------------------------- L5 softmax (compacted)
__global__ LB256 void softmax_c(f16* __restrict__ S, const int* __restrict__ counts,
                                const int* __restrict__ npad) {
  __shared__ float red[4];
  const long r = blockIdx.x;
  const int b = (int)(r >> 11);
  const int nv = counts[b], np = npad[b];
  f16* row = S + r * 2048;
  const int t = threadIdx.x;
  const bool act = (t * 8) < np;

  float v[8];
  float mx = -3.0e38f;
  if (act) {
    f16x8 sv = *(const f16x8*)(row + t * 8);
#pragma unroll
    for (int e = 0; e < 8; ++e) {
      float s = (t * 8 + e < nv) ? (float)sv[e] : -3.0e38f;
      v[e] = s;
      mx = fmaxf(mx, s);
    }
  } else {
#pragma unroll
    for (int e = 0; e < 8; ++e) v[e] = -3.0e38f;
  }
#pragma unroll
  for (int off = 32; off > 0; off >>= 1) mx = fmaxf(mx, __shfl_xor(mx, off, 64));
  if ((t & 63) == 0) red[t >> 6] = mx;
  __syncthreads();
  mx = fmaxf(fmaxf(red[0], red[1]), fmaxf(red[2], red[3]));
  __syncthreads();

  float e[8];
  float sum = 0.f;
#pragma unroll
  for (int it = 0; it < 8; ++it) {
    float ev = (v[it] <= -1.0e38f) ? 0.f : __expf(v[it] - mx);
    e[it] = ev;
    sum += ev;
  }
#pragma unroll
  for (int off = 32; off > 0; off >>= 1) sum += __shfl_xor(sum, off, 64);
  if ((t & 63) == 0) red[t >> 6] = sum;
  __syncthreads();
  sum = red[0] + red[1] + red[2] + red[3];
  if (act) {
    const float inv = 1.f / sum;
    f16x8 ov;
#pragma unroll
    for (int it = 0; it < 8; ++it) ov[it] = (f16)(e[it] * inv);
    *(f16x8*)(row + t * 8) = ov;
  }
}

// ---------------------------------------------------------------- L6 PV GEMM
__global__ __launch_bounds__(256, 4) void pv_gemm(
    const f16* __restrict__ Sbuf, const f16* __restrict__ Vt,
    float* __restrict__ out, const int* __restrict__ npad) {
  const int z = blockIdx.z;
  gemm_body<float>(Sbuf + (long)z * 2048 * 2048, 2048, Vt + (long)z * 1024 * 2048,
                   2048, out + (long)z * 2048 * 1024, 1024, nullptr, nullptr, 0, 0,
                   1.0f, npad[z], blockIdx.y * 128, blockIdx.x * 128);
}

// ---------------------------------------------------------------- launch
extern "C" void kernel_launch(void* const* d_in, const int* in_sizes, int n_in,
                              void* d_out, int out_size, void* d_ws, size_t ws_size,
                              hipStream_t stream) {
  const float* x = (const float*)d_in[0];
  const void* mask = d_in[1];
  const float* Wq = (const float*)d_in[2];
  const float* bq = (const float*)d_in[3];
  const float* Wk = (const float*)d_in[4];
  const float* bk = (const float*)d_in[5];
  const float* Wv = (const float*)d_in[6];
  const float* bv = (const float*)d_in[7];
  float* out = (float*)d_out;

  // Workspace (f16 elems), ~86 MB. Sbuf (32 MB) aliases xh+xc (dead before L4's S).
  f16* xh = (f16*)d_ws;              // 8M  [0,16MB)
  f16* xc = xh + 8388608;            // 8M  [16,32)
  f16* Sbuf = xh;                    // 16M [0,32) alias -- NOTE: svt reads xc!
  f16* Wh = xc + 8388608;            // 3M  [32,38)  [Wq|Wk|Wv]
  f16* Qb = Wh + 3145728;            // 8M  [38,54)
  f16* Kc = Qb + 8388608;            // 8M  [54,70)
  f16* Vt = Kc + 8388608;            // 8M  [70,86)
  int* sel = (int*)(Vt + 8388608);   // 8192
  int* counts = sel + 8192;          // 4
  int* npad = counts + 4;            // 4

  // HAZARD CHECK: svt writes Sbuf (aliases xh+xc) while vt-tiles READ xc.
  // S tile (b,m,n) writes Sbuf[b*2048*2048 + ...] -> f16 offset range
  // [b*4M, (b+1)*4M) = bytes [b*8MB, b*8MB+8MB). xc lives at bytes [16,32) MB
  // = Sbuf of batches 2,3. So vt-tiles of batch z read bytes [16+z*4MB...]
  // while S-tiles of batches 2,3 write the same range -> RACE. Fix: place Sbuf
  // in batch order {2,3,0,1} so S(b) writes land where xc(b) lives AFTER vt(b)
  // is done? Still racy across batches. Instead: Sbuf gets its own region.
  // ws proven >= 118 MB in R1 (layout used 118 MB); 86+32=118 MB fits exactly.
  Sbuf = Vt + 8388608;               // 16M [86,118) -- no aliasing
  sel = (int*)(Sbuf + 16777216);
  counts = sel + 8192;
  npad = counts + 4;

  prep<<<11268, 256, 0, stream>>>(x, Wq, Wk, Wv, mask, xh, Wh, sel, counts, npad);
  gather_x<<<dim3(512, 4), 256, 0, stream>>>(xh, sel, counts, npad, xc);
  qk_gemm<<<1024, 256, 0, stream>>>(xh, xc, Wh, Qb, Kc, bq, bk, npad);
  svt_gemm<<<1536, 256, 0, stream>>>(Qb, Kc, Sbuf, Wh, xc, Vt, bv, npad);
  softmax_c<<<8192, 256, 0, stream>>>(Sbuf, counts, npad);
  pv_gemm<<<dim3(8, 16, 4), 256, 0, stream>>>(Sbuf, Vt, out, npad);
}